// Round 5
// baseline (380.807 us; speedup 1.0000x reference)
//
#include <hip/hip_runtime.h>
#include <hip/hip_bf16.h>

#define BN 4
#define CC 128
#define SS 4096
#define L2E 1.44269504f

typedef _Float16 f16;
typedef f16 f16x8 __attribute__((ext_vector_type(8)));
typedef float f32x4 __attribute__((ext_vector_type(4)));

// ---------------------------------------------------------------- prep
struct WPrep { const float *w, *b, *sc, *bb, *bm, *bv; };

// Weff[p][o][c] = W[o][c]*inv[o] (f16);  eb[p][o] = (b-bm)*inv + bb (f32)
__global__ __launch_bounds__(256) void prep_kernel(WPrep p0, WPrep p1, WPrep p2,
                                                   f16* __restrict__ Weff, float* __restrict__ eb) {
    const int bx = blockIdx.x;
    const int p = bx >> 6, sub = bx & 63;
    WPrep P = (p == 0) ? p0 : ((p == 1) ? p1 : p2);
    int idx = sub * 256 + threadIdx.x;          // 0..16383
    int o = idx >> 7, c = idx & 127;
    float inv = P.sc[o] * rsqrtf(P.bv[o] + 1e-5f);
    Weff[p * 16384 + idx] = (f16)(P.w[o * CC + c] * inv);
    if (sub == 0 && threadIdx.x < 128) {
        int t = threadIdx.x;
        float invt = P.sc[t] * rsqrtf(P.bv[t] + 1e-5f);
        eb[p * 128 + t] = (P.b[t] - P.bm[t]) * invt + P.bb[t];
    }
}

// ---------------------------------------------------------------- proj (MFMA)
// grid (256, 3): y=p, x = b*64 + st (64-position tiles). 256 threads (4 waves).
// p=0,1 -> position-major out [B][S][C]; p=2 -> channel-major out [B][C][S].
__global__ __launch_bounds__(256) void proj_kernel(
    const float* __restrict__ xq, const float* __restrict__ xk, const float* __restrict__ xv,
    const f16* __restrict__ Weff, const float* __restrict__ eb,
    f16* __restrict__ Qt, f16* __restrict__ Kt, f16* __restrict__ Vt)
{
    const int p  = blockIdx.y;
    const int bx = blockIdx.x;
    const int b  = bx >> 6;
    const int s0 = (bx & 63) * 64;
    const int tid = threadIdx.x;
    const int w = tid >> 6, lane = tid & 63;
    const int n = lane & 15, g = lane >> 4;

    const float* X = (p == 0) ? xq : ((p == 1) ? xk : xv);
    f16* out = (p == 0) ? Qt : ((p == 1) ? Kt : Vt);

    __shared__ f16 Xl[64][136];                 // X^T tile: [s][c]
    __shared__ f16 Wl[128][136];                // Weff: [o][c]  (aliased as Yl later)
    f16* Yl = &Wl[0][0];

    // stage X (transpose fp32 [c][s] -> f16 [s][c])
#pragma unroll
    for (int i = 0; i < 8; ++i) {
        int vi = tid + i * 256;                 // 0..2047
        int c = vi >> 4, sq = (vi & 15) * 4;
        float4 v = *(const float4*)(X + ((size_t)b * CC + c) * SS + s0 + sq);
        Xl[sq + 0][c] = (f16)v.x; Xl[sq + 1][c] = (f16)v.y;
        Xl[sq + 2][c] = (f16)v.z; Xl[sq + 3][c] = (f16)v.w;
    }
    // stage Weff
#pragma unroll
    for (int i = 0; i < 8; ++i) {
        int vi = tid + i * 256;
        int o = vi >> 4, cl = (vi & 15) * 8;
        *(uint4*)&Wl[o][cl] = *(const uint4*)&Weff[p * 16384 + o * CC + cl];
    }
    __syncthreads();

    if (p < 2) {
        // D[m=o][n=s]: A=Weff, B=X. Wave w: o in [w*32, w*32+32), all 64 s.
        f32x4 acc[2][4];
#pragma unroll
        for (int mt = 0; mt < 2; ++mt)
#pragma unroll
            for (int nt = 0; nt < 4; ++nt) acc[mt][nt] = (f32x4){0.f, 0.f, 0.f, 0.f};
#pragma unroll
        for (int ks = 0; ks < 4; ++ks) {
            f16x8 af[2], bf[4];
#pragma unroll
            for (int mt = 0; mt < 2; ++mt) af[mt] = *(const f16x8*)&Wl[w * 32 + mt * 16 + n][ks * 32 + g * 8];
#pragma unroll
            for (int nt = 0; nt < 4; ++nt) bf[nt] = *(const f16x8*)&Xl[nt * 16 + n][ks * 32 + g * 8];
#pragma unroll
            for (int mt = 0; mt < 2; ++mt)
#pragma unroll
                for (int nt = 0; nt < 4; ++nt)
                    acc[mt][nt] = __builtin_amdgcn_mfma_f32_16x16x32_f16(af[mt], bf[nt], acc[mt][nt], 0, 0, 0);
        }
        __syncthreads();                        // all Wl reads done before Yl overwrite
        // epilogue: bias + ELU, pack rows (o) -> Yl[s][o]
#pragma unroll
        for (int mt = 0; mt < 2; ++mt) {
            float ebr[4];
#pragma unroll
            for (int r = 0; r < 4; ++r) ebr[r] = eb[p * 128 + w * 32 + mt * 16 + g * 4 + r];
#pragma unroll
            for (int nt = 0; nt < 4; ++nt) {
                union { f16 h[4]; uint2 u; } pk;
#pragma unroll
                for (int r = 0; r < 4; ++r) {
                    float y = acc[mt][nt][r] + ebr[r];
                    y = (y > 0.f) ? y : (expf(y) - 1.f);
                    pk.h[r] = (f16)y;
                }
                *(uint2*)&Yl[(nt * 16 + n) * 136 + w * 32 + mt * 16 + g * 4] = pk.u;
            }
        }
        __syncthreads();
        // store position-major [b][s][o]
#pragma unroll
        for (int i = 0; i < 4; ++i) {
            int vi = tid + i * 256;             // 0..1023
            int s = vi >> 4, cl = (vi & 15) * 8;
            *(uint4*)&out[((size_t)b * SS + s0 + s) * CC + cl] = *(const uint4*)&Yl[s * 136 + cl];
        }
    } else {
        // D[m=s][n=o]: A=X, B=Weff. Wave w: s in [w*16, w*16+16), all 128 o.
        f32x4 acc[8];
#pragma unroll
        for (int nt = 0; nt < 8; ++nt) acc[nt] = (f32x4){0.f, 0.f, 0.f, 0.f};
#pragma unroll
        for (int ks = 0; ks < 4; ++ks) {
            f16x8 af = *(const f16x8*)&Xl[w * 16 + n][ks * 32 + g * 8];
#pragma unroll
            for (int nt = 0; nt < 8; ++nt) {
                f16x8 bf = *(const f16x8*)&Wl[nt * 16 + n][ks * 32 + g * 8];
                acc[nt] = __builtin_amdgcn_mfma_f32_16x16x32_f16(af, bf, acc[nt], 0, 0, 0);
            }
        }
        __syncthreads();
#pragma unroll
        for (int nt = 0; nt < 8; ++nt) {
            float ebc = eb[p * 128 + nt * 16 + n];
            union { f16 h[4]; uint2 u; } pk;
#pragma unroll
            for (int r = 0; r < 4; ++r) {
                float y = acc[nt][r] + ebc;
                y = (y > 0.f) ? y : (expf(y) - 1.f);
                pk.h[r] = (f16)y;
            }
            *(uint2*)&Yl[(nt * 16 + n) * 136 + w * 16 + g * 4] = pk.u;   // Yl[o][s]
        }
        __syncthreads();
        // store channel-major [b][o][s]
#pragma unroll
        for (int i = 0; i < 4; ++i) {
            int vi = tid + i * 256;             // 0..1023
            int o = vi >> 3, sl = (vi & 7) * 8;
            *(uint4*)&out[((size_t)b * CC + o) * SS + s0 + sl] = *(const uint4*)&Yl[o * 136 + sl];
        }
    }
}

// ---------------------------------------------------------------- attention
// grid 512, 128 threads (2 waves). bx = b*128 + qt*2 + kh; q-tile 64, wave owns 32 q.
// In-register online softmax; P via wave-private LDS region (no barrier).
__global__ __launch_bounds__(128, 2) void attn_kernel(
    const f16* __restrict__ Qt, const f16* __restrict__ Kt, const f16* __restrict__ Vt,
    f16* __restrict__ Op, float* __restrict__ Ml)
{
    const int tid = threadIdx.x;
    const int bx = blockIdx.x;
    const int b  = bx >> 7;
    const int qt = (bx & 127) >> 1;
    const int kh = bx & 1;
    const int q0 = qt * 64;
    const int kbeg = kh * (SS / 2);

    __shared__ f16 Kl[64][136];                 // K tile [key][c] (also Q staging)
    __shared__ f16 Vl[128][72];                 // V tile [c][key]
    __shared__ f16 Pl[2][32][72];               // per-wave P [q_local][key]

    const int w = tid >> 6, lane = tid & 63;
    const int n = lane & 15, g = lane >> 4;

    // stage Q into Kl, preload A-frags
#pragma unroll
    for (int i = 0; i < 8; ++i) {
        int vi = tid + i * 128;
        int r = vi >> 4, cl = (vi & 15) * 8;
        *(uint4*)&Kl[r][cl] = *(const uint4*)&Qt[((size_t)b * SS + q0 + r) * CC + cl];
    }
    __syncthreads();
    f16x8 qf[2][4];
#pragma unroll
    for (int mt = 0; mt < 2; ++mt)
#pragma unroll
        for (int ks = 0; ks < 4; ++ks)
            qf[mt][ks] = *(const f16x8*)&Kl[w * 32 + mt * 16 + n][ks * 32 + g * 8];

    f32x4 oacc[2][8];
#pragma unroll
    for (int mt = 0; mt < 2; ++mt)
#pragma unroll
        for (int nt = 0; nt < 8; ++nt) oacc[mt][nt] = (f32x4){0.f, 0.f, 0.f, 0.f};
    float mreg[2][4], lreg[2][4];
#pragma unroll
    for (int mt = 0; mt < 2; ++mt)
#pragma unroll
        for (int r = 0; r < 4; ++r) { mreg[mt][r] = -1e30f; lreg[mt][r] = 0.f; }

    for (int kt = 0; kt < (SS / 2) / 64; ++kt) {
        const int k0 = kbeg + kt * 64;
        __syncthreads();                        // prev-step reads (and qf preload) done
#pragma unroll
        for (int i = 0; i < 8; ++i) {
            int vi = tid + i * 128;
            int rk = vi >> 4, ck = (vi & 15) * 8;
            *(uint4*)&Kl[rk][ck] = *(const uint4*)&Kt[((size_t)b * SS + k0 + rk) * CC + ck];
            int rv = vi >> 3, cv = (vi & 7) * 8;
            *(uint4*)&Vl[rv][cv] = *(const uint4*)&Vt[((size_t)b * CC + rv) * SS + k0 + cv];
        }
        __syncthreads();                        // tiles ready

        // phase A: S[q][key] = Q.K^T
        f32x4 sacc[2][4];
#pragma unroll
        for (int mt = 0; mt < 2; ++mt)
#pragma unroll
            for (int nt = 0; nt < 4; ++nt) sacc[mt][nt] = (f32x4){0.f, 0.f, 0.f, 0.f};
#pragma unroll
        for (int ks = 0; ks < 4; ++ks) {
            f16x8 kf[4];
#pragma unroll
            for (int nt = 0; nt < 4; ++nt) kf[nt] = *(const f16x8*)&Kl[nt * 16 + n][ks * 32 + g * 8];
#pragma unroll
            for (int mt = 0; mt < 2; ++mt)
#pragma unroll
                for (int nt = 0; nt < 4; ++nt)
                    sacc[mt][nt] = __builtin_amdgcn_mfma_f32_16x16x32_f16(qf[mt][ks], kf[nt], sacc[mt][nt], 0, 0, 0);
        }

        // in-register online softmax (rows q = w*32 + mt*16 + g*4 + r)
        float al[2][4];
#pragma unroll
        for (int mt = 0; mt < 2; ++mt) {
#pragma unroll
            for (int r = 0; r < 4; ++r) {
                float v = fmaxf(fmaxf(sacc[mt][0][r], sacc[mt][1][r]),
                                fmaxf(sacc[mt][2][r], sacc[mt][3][r]));
                v = fmaxf(v, __shfl_xor(v, 1));
                v = fmaxf(v, __shfl_xor(v, 2));
                v = fmaxf(v, __shfl_xor(v, 4));
                v = fmaxf(v, __shfl_xor(v, 8));
                float mn = fmaxf(mreg[mt][r], v);
                al[mt][r] = exp2f((mreg[mt][r] - mn) * L2E);
                mreg[mt][r] = mn;
                float p[4], rs = 0.f;
#pragma unroll
                for (int nt = 0; nt < 4; ++nt) {
                    p[nt] = exp2f((sacc[mt][nt][r] - mn) * L2E);
                    rs += p[nt];
                    Pl[w][mt * 16 + g * 4 + r][nt * 16 + n] = (f16)p[nt];
                }
                rs += __shfl_xor(rs, 1);
                rs += __shfl_xor(rs, 2);
                rs += __shfl_xor(rs, 4);
                rs += __shfl_xor(rs, 8);
                lreg[mt][r] = lreg[mt][r] * al[mt][r] + rs;
            }
        }
        // O rescale
#pragma unroll
        for (int mt = 0; mt < 2; ++mt)
#pragma unroll
            for (int nt = 0; nt < 8; ++nt)
#pragma unroll
                for (int r = 0; r < 4; ++r) oacc[mt][nt][r] *= al[mt][r];

        // phase B: O[q][c] += P.V^T (A=P from own Pl region, B=V)
#pragma unroll
        for (int ks = 0; ks < 2; ++ks) {
            f16x8 af2[2], vf[8];
#pragma unroll
            for (int mt = 0; mt < 2; ++mt) af2[mt] = *(const f16x8*)&Pl[w][mt * 16 + n][ks * 32 + g * 8];
#pragma unroll
            for (int nt = 0; nt < 8; ++nt) vf[nt] = *(const f16x8*)&Vl[nt * 16 + n][ks * 32 + g * 8];
#pragma unroll
            for (int mt = 0; mt < 2; ++mt)
#pragma unroll
                for (int nt = 0; nt < 8; ++nt)
                    oacc[mt][nt] = __builtin_amdgcn_mfma_f32_16x16x32_f16(af2[mt], vf[nt], oacc[mt][nt], 0, 0, 0);
        }
    }

    // epilogue: O^T[c][q] partial (f16, pack 4 q) + m,l
    f16* OpW = Op + ((size_t)(b * 64 + qt) * 2 + kh) * 8192;
#pragma unroll
    for (int mt = 0; mt < 2; ++mt)
#pragma unroll
        for (int nt = 0; nt < 8; ++nt) {
            int c = nt * 16 + n;
            int qb = w * 32 + mt * 16 + g * 4;
            union { f16 h[4]; uint2 u; } pk;
#pragma unroll
            for (int r = 0; r < 4; ++r) pk.h[r] = (f16)oacc[mt][nt][r];
            *(uint2*)&OpW[c * 64 + qb] = pk.u;
        }
    if (n == 0) {
        float* MlW = Ml + (size_t)(b * 64 + qt) * 256 + kh * 128;
#pragma unroll
        for (int mt = 0; mt < 2; ++mt)
#pragma unroll
            for (int r = 0; r < 4; ++r) {
                int q = w * 32 + mt * 16 + g * 4 + r;
                MlW[q]      = mreg[mt][r];
                MlW[64 + q] = lreg[mt][r];
            }
    }
}

// ---------------------------------------------------------------- merge
__global__ __launch_bounds__(256) void merge_kernel(
    const f16* __restrict__ Op, const float* __restrict__ Ml,
    const float* __restrict__ xv, const float* __restrict__ gp, const float* __restrict__ bp,
    float* __restrict__ out)
{
    const int bq = blockIdx.x;                 // b*64 + qt
    const int b = bq >> 6, qt = bq & 63;
    const int t = threadIdx.x;
    const int q = t & 63, cg = t >> 6;

    const float* ml = Ml + (size_t)bq * 256;
    float m1 = ml[q], l1 = ml[64 + q], m2 = ml[128 + q], l2 = ml[192 + q];
    float m = fmaxf(m1, m2);
    float w1 = exp2f((m1 - m) * L2E), w2 = exp2f((m2 - m) * L2E);
    float inv = 1.f / (w1 * l1 + w2 * l2);
    float gm = gp[0], bb = bp[0];

    const f16* O1 = Op + (size_t)bq * 2 * 8192;
    const f16* O2 = O1 + 8192;
#pragma unroll 4
    for (int i = 0; i < 32; ++i) {
        int c = cg * 32 + i;
        float o = (w1 * (float)O1[c * 64 + q] + w2 * (float)O2[c * 64 + q]) * inv;
        size_t idx = ((size_t)(b * CC + c)) * SS + qt * 64 + q;
        out[idx] = gm * o + bb * xv[idx];
    }
}

// ---------------------------------------------------------------- launcher
extern "C" void kernel_launch(void* const* d_in, const int* in_sizes, int n_in,
                              void* d_out, int out_size, void* d_ws, size_t ws_size,
                              hipStream_t stream) {
    (void)in_sizes; (void)n_in; (void)out_size; (void)ws_size;

    const size_t TEN = (size_t)BN * SS * CC;         // 2,097,152
    f16* Qt = (f16*)d_ws;                            // 4 MB
    f16* Kt = Qt + TEN;                              // 4 MB
    f16* Vt = Kt + TEN;                              // 4 MB (channel-major)
    f16* Op = Vt + TEN;                              // 512*8192 f16 = 8 MB
    float* Ml = (float*)(Op + (size_t)512 * 8192);   // 512 KB
    f16* Weff = (f16*)(Ml + 131072);                 // 3*16384 f16 = 96 KB
    float* ebv = (float*)(Weff + 49152);             // 384 f32

    WPrep pq = { (const float*)d_in[3],  (const float*)d_in[4],  (const float*)d_in[5],
                 (const float*)d_in[6],  (const float*)d_in[7],  (const float*)d_in[8] };
    WPrep pk = { (const float*)d_in[9],  (const float*)d_in[10], (const float*)d_in[11],
                 (const float*)d_in[12], (const float*)d_in[13], (const float*)d_in[14] };
    WPrep pv = { (const float*)d_in[15], (const float*)d_in[16], (const float*)d_in[17],
                 (const float*)d_in[18], (const float*)d_in[19], (const float*)d_in[20] };

    hipLaunchKernelGGL(prep_kernel, dim3(192), dim3(256), 0, stream, pq, pk, pv, Weff, ebv);
    hipLaunchKernelGGL(proj_kernel, dim3(256, 3), dim3(256), 0, stream,
                       (const float*)d_in[0], (const float*)d_in[1], (const float*)d_in[2],
                       Weff, ebv, Qt, Kt, Vt);
    hipLaunchKernelGGL(attn_kernel, dim3(512), dim3(128), 0, stream, Qt, Kt, Vt, Op, Ml);
    hipLaunchKernelGGL(merge_kernel, dim3(256), dim3(256), 0, stream,
                       Op, Ml, (const float*)d_in[2], (const float*)d_in[21],
                       (const float*)d_in[22], (float*)d_out);
}

// Round 6
// 230.820 us; speedup vs baseline: 1.6498x; 1.6498x over previous
//
#include <hip/hip_runtime.h>
#include <hip/hip_bf16.h>

#define BN 4
#define CC 128
#define SS 4096
#define L2E 1.44269504f

typedef _Float16 f16;
typedef f16 f16x8 __attribute__((ext_vector_type(8)));
typedef float f32x4 __attribute__((ext_vector_type(4)));

// ---------------------------------------------------------------- prep
struct WPrep { const float *w, *b, *sc, *bb, *bm, *bv; };

__global__ __launch_bounds__(256) void prepk(WPrep p0, WPrep p1, WPrep p2,
                                             f16* __restrict__ Weff, float* __restrict__ eb) {
    const int bx = blockIdx.x;
    const int p = bx >> 6, sub = bx & 63;
    WPrep P = (p == 0) ? p0 : ((p == 1) ? p1 : p2);
    int idx = sub * 256 + threadIdx.x;          // 0..16383
    int o = idx >> 7;
    float inv = P.sc[o] * rsqrtf(P.bv[o] + 1e-5f);
    Weff[p * 16384 + idx] = (f16)(P.w[idx] * inv);
    if (sub == 0 && threadIdx.x < 128) {
        int t = threadIdx.x;
        float invt = P.sc[t] * rsqrtf(P.bv[t] + 1e-5f);
        eb[p * 128 + t] = (P.b[t] - P.bm[t]) * invt + P.bb[t];
    }
}

// ---------------------------------------------------------------- proj (MFMA)
// grid (256, 3): y=p, x = b*64 + st. p=0,1 -> [B][S][C]; p=2 -> [B][C][S].
__global__ __launch_bounds__(256) void projk(
    const float* __restrict__ xq, const float* __restrict__ xk, const float* __restrict__ xv,
    const f16* __restrict__ Weff, const float* __restrict__ eb,
    f16* __restrict__ Qt, f16* __restrict__ Kt, f16* __restrict__ Vt)
{
    const int p  = blockIdx.y;
    const int bx = blockIdx.x;
    const int b  = bx >> 6;
    const int s0 = (bx & 63) * 64;
    const int tid = threadIdx.x;
    const int w = tid >> 6, lane = tid & 63;
    const int n = lane & 15, g = lane >> 4;

    const float* X = (p == 0) ? xq : ((p == 1) ? xk : xv);
    f16* out = (p == 0) ? Qt : ((p == 1) ? Kt : Vt);

    __shared__ f16 Xl[64][136];                 // X^T tile: [s][c]
    __shared__ f16 Wl[128][136];                // Weff [o][c], aliased as Yl
    f16* Yl = &Wl[0][0];

#pragma unroll
    for (int i = 0; i < 8; ++i) {
        int vi = tid + i * 256;                 // 0..2047
        int c = vi >> 4, sq = (vi & 15) * 4;
        float4 v = *(const float4*)(X + ((size_t)b * CC + c) * SS + s0 + sq);
        Xl[sq + 0][c] = (f16)v.x; Xl[sq + 1][c] = (f16)v.y;
        Xl[sq + 2][c] = (f16)v.z; Xl[sq + 3][c] = (f16)v.w;
    }
#pragma unroll
    for (int i = 0; i < 8; ++i) {
        int vi = tid + i * 256;
        int o = vi >> 4, cl = (vi & 15) * 8;
        *(uint4*)&Wl[o][cl] = *(const uint4*)&Weff[p * 16384 + o * CC + cl];
    }
    __syncthreads();

    if (p < 2) {
        f32x4 acc[2][4];
#pragma unroll
        for (int mt = 0; mt < 2; ++mt)
#pragma unroll
            for (int nt = 0; nt < 4; ++nt) acc[mt][nt] = (f32x4){0.f, 0.f, 0.f, 0.f};
#pragma unroll
        for (int ks = 0; ks < 4; ++ks) {
            f16x8 af[2], bf[4];
#pragma unroll
            for (int mt = 0; mt < 2; ++mt) af[mt] = *(const f16x8*)&Wl[w * 32 + mt * 16 + n][ks * 32 + g * 8];
#pragma unroll
            for (int nt = 0; nt < 4; ++nt) bf[nt] = *(const f16x8*)&Xl[nt * 16 + n][ks * 32 + g * 8];
#pragma unroll
            for (int mt = 0; mt < 2; ++mt)
#pragma unroll
                for (int nt = 0; nt < 4; ++nt)
                    acc[mt][nt] = __builtin_amdgcn_mfma_f32_16x16x32_f16(af[mt], bf[nt], acc[mt][nt], 0, 0, 0);
        }
        __syncthreads();
#pragma unroll
        for (int mt = 0; mt < 2; ++mt) {
            float ebr[4];
#pragma unroll
            for (int r = 0; r < 4; ++r) ebr[r] = eb[p * 128 + w * 32 + mt * 16 + g * 4 + r];
#pragma unroll
            for (int nt = 0; nt < 4; ++nt) {
                union { f16 h[4]; uint2 u; } pk;
#pragma unroll
                for (int r = 0; r < 4; ++r) {
                    float y = acc[mt][nt][r] + ebr[r];
                    y = (y > 0.f) ? y : (expf(y) - 1.f);
                    pk.h[r] = (f16)y;
                }
                *(uint2*)&Yl[(nt * 16 + n) * 136 + w * 32 + mt * 16 + g * 4] = pk.u;
            }
        }
        __syncthreads();
#pragma unroll
        for (int i = 0; i < 4; ++i) {
            int vi = tid + i * 256;
            int s = vi >> 4, cl = (vi & 15) * 8;
            *(uint4*)&out[((size_t)b * SS + s0 + s) * CC + cl] = *(const uint4*)&Yl[s * 136 + cl];
        }
    } else {
        f32x4 acc[8];
#pragma unroll
        for (int nt = 0; nt < 8; ++nt) acc[nt] = (f32x4){0.f, 0.f, 0.f, 0.f};
#pragma unroll
        for (int ks = 0; ks < 4; ++ks) {
            f16x8 af = *(const f16x8*)&Xl[w * 16 + n][ks * 32 + g * 8];
#pragma unroll
            for (int nt = 0; nt < 8; ++nt) {
                f16x8 bf = *(const f16x8*)&Wl[nt * 16 + n][ks * 32 + g * 8];
                acc[nt] = __builtin_amdgcn_mfma_f32_16x16x32_f16(af, bf, acc[nt], 0, 0, 0);
            }
        }
        __syncthreads();
#pragma unroll
        for (int nt = 0; nt < 8; ++nt) {
            float ebc = eb[p * 128 + nt * 16 + n];
            union { f16 h[4]; uint2 u; } pk;
#pragma unroll
            for (int r = 0; r < 4; ++r) {
                float y = acc[nt][r] + ebc;
                y = (y > 0.f) ? y : (expf(y) - 1.f);
                pk.h[r] = (f16)y;
            }
            *(uint2*)&Yl[(nt * 16 + n) * 136 + w * 16 + g * 4] = pk.u;   // Yl[o][s]
        }
        __syncthreads();
#pragma unroll
        for (int i = 0; i < 4; ++i) {
            int vi = tid + i * 256;
            int o = vi >> 3, sl = (vi & 7) * 8;
            *(uint4*)&out[((size_t)b * CC + o) * SS + s0 + sl] = *(const uint4*)&Yl[o * 136 + sl];
        }
    }
}

// ---------------------------------------------------------------- attention
// grid 512 = b(4) x kh(4) x qt(32), qt fastest (L2 locality on K/V range).
// 256 threads (4 waves). q-tile 128: wave owns 32 q (mt=2). 1024 keys, 16 steps of 64.
__global__ __launch_bounds__(256, 2) void attnk(
    const f16* __restrict__ Qt, const f16* __restrict__ Kt, const f16* __restrict__ Vt,
    f16* __restrict__ Op, float* __restrict__ Ml)
{
    const int tid = threadIdx.x;
    const int bx = blockIdx.x;
    const int b  = bx >> 7;
    const int kh = (bx >> 5) & 3;
    const int qt = bx & 31;
    const int q0 = qt * 128;
    const int kbeg = kh * 1024;

    __shared__ f16 Kl[64][136];                 // K tile [key][c]
    __shared__ f16 Vl[128][72];                 // V tile [c][key]
    __shared__ f16 Pl[4][32][72];               // per-wave P [q_local][key]

    const int w = tid >> 6, lane = tid & 63;
    const int n = lane & 15, g = lane >> 4;

    // Q fragments straight from global (L2-warm): A[m=q][k=c]
    f16x8 qf[2][4];
    {
        const f16* Qb = Qt + ((size_t)b * SS + q0 + w * 32) * CC;
#pragma unroll
        for (int mt = 0; mt < 2; ++mt)
#pragma unroll
            for (int ks = 0; ks < 4; ++ks)
                qf[mt][ks] = *(const f16x8*)&Qb[(mt * 16 + n) * CC + ks * 32 + g * 8];
    }

    f32x4 oacc[2][8];
#pragma unroll
    for (int mt = 0; mt < 2; ++mt)
#pragma unroll
        for (int nt = 0; nt < 8; ++nt) oacc[mt][nt] = (f32x4){0.f, 0.f, 0.f, 0.f};
    float mreg[2][4], lreg[2][4];
#pragma unroll
    for (int mt = 0; mt < 2; ++mt)
#pragma unroll
        for (int r = 0; r < 4; ++r) { mreg[mt][r] = -1e30f; lreg[mt][r] = 0.f; }

    for (int kt = 0; kt < 16; ++kt) {
        const int k0 = kbeg + kt * 64;
        __syncthreads();                        // prev-step LDS reads done
#pragma unroll
        for (int i = 0; i < 4; ++i) {
            int vi = tid + i * 256;             // 0..1023
            int rk = vi >> 4, ck = (vi & 15) * 8;
            *(uint4*)&Kl[rk][ck] = *(const uint4*)&Kt[((size_t)b * SS + k0 + rk) * CC + ck];
            int rv = vi >> 3, cv = (vi & 7) * 8;
            *(uint4*)&Vl[rv][cv] = *(const uint4*)&Vt[((size_t)b * CC + rv) * SS + k0 + cv];
        }
        __syncthreads();                        // tiles ready

        // phase A: S[q][key] = Q.K^T  (all 64 keys, wave's 32 q)
        f32x4 sacc[2][4];
#pragma unroll
        for (int mt = 0; mt < 2; ++mt)
#pragma unroll
            for (int nt = 0; nt < 4; ++nt) sacc[mt][nt] = (f32x4){0.f, 0.f, 0.f, 0.f};
#pragma unroll
        for (int ks = 0; ks < 4; ++ks) {
            f16x8 kf[4];
#pragma unroll
            for (int nt = 0; nt < 4; ++nt) kf[nt] = *(const f16x8*)&Kl[nt * 16 + n][ks * 32 + g * 8];
#pragma unroll
            for (int mt = 0; mt < 2; ++mt)
#pragma unroll
                for (int nt = 0; nt < 4; ++nt)
                    sacc[mt][nt] = __builtin_amdgcn_mfma_f32_16x16x32_f16(qf[mt][ks], kf[nt], sacc[mt][nt], 0, 0, 0);
        }

        // in-register online softmax; rows q_local = mt*16 + g*4 + r
        float al[2][4];
#pragma unroll
        for (int mt = 0; mt < 2; ++mt) {
#pragma unroll
            for (int r = 0; r < 4; ++r) {
                float v = fmaxf(fmaxf(sacc[mt][0][r], sacc[mt][1][r]),
                                fmaxf(sacc[mt][2][r], sacc[mt][3][r]));
                v = fmaxf(v, __shfl_xor(v, 1));
                v = fmaxf(v, __shfl_xor(v, 2));
                v = fmaxf(v, __shfl_xor(v, 4));
                v = fmaxf(v, __shfl_xor(v, 8));
                float mn = fmaxf(mreg[mt][r], v);
                al[mt][r] = exp2f((mreg[mt][r] - mn) * L2E);
                mreg[mt][r] = mn;
                float p[4], rs = 0.f;
#pragma unroll
                for (int nt = 0; nt < 4; ++nt) {
                    p[nt] = exp2f((sacc[mt][nt][r] - mn) * L2E);
                    rs += p[nt];
                    Pl[w][mt * 16 + g * 4 + r][nt * 16 + n] = (f16)p[nt];
                }
                rs += __shfl_xor(rs, 1);
                rs += __shfl_xor(rs, 2);
                rs += __shfl_xor(rs, 4);
                rs += __shfl_xor(rs, 8);
                lreg[mt][r] = lreg[mt][r] * al[mt][r] + rs;
            }
        }
#pragma unroll
        for (int mt = 0; mt < 2; ++mt)
#pragma unroll
            for (int nt = 0; nt < 8; ++nt)
#pragma unroll
                for (int r = 0; r < 4; ++r) oacc[mt][nt][r] *= al[mt][r];

        // phase B: O[q][c] += P.V^T (Pl wave-private: no barrier needed)
#pragma unroll
        for (int ks = 0; ks < 2; ++ks) {
            f16x8 af2[2], vf[8];
#pragma unroll
            for (int mt = 0; mt < 2; ++mt) af2[mt] = *(const f16x8*)&Pl[w][mt * 16 + n][ks * 32 + g * 8];
#pragma unroll
            for (int nt = 0; nt < 8; ++nt) vf[nt] = *(const f16x8*)&Vl[nt * 16 + n][ks * 32 + g * 8];
#pragma unroll
            for (int mt = 0; mt < 2; ++mt)
#pragma unroll
                for (int nt = 0; nt < 8; ++nt)
                    oacc[mt][nt] = __builtin_amdgcn_mfma_f32_16x16x32_f16(af2[mt], vf[nt], oacc[mt][nt], 0, 0, 0);
        }
    }

    // epilogue: partial O^T [c][q] (f16) + m,l per (b,qt,kh)
    f16* OpW = Op + (((size_t)(b * 32 + qt)) * 4 + kh) * 16384;
#pragma unroll
    for (int mt = 0; mt < 2; ++mt)
#pragma unroll
        for (int nt = 0; nt < 8; ++nt) {
            int c = nt * 16 + n;
            int qb = w * 32 + mt * 16 + g * 4;
            union { f16 h[4]; uint2 u; } pk;
#pragma unroll
            for (int r = 0; r < 4; ++r) pk.h[r] = (f16)oacc[mt][nt][r];
            *(uint2*)&OpW[c * 128 + qb] = pk.u;
        }
    if (n == 0) {
        float* MlW = Ml + (((size_t)(b * 32 + qt)) * 4 + kh) * 256;
#pragma unroll
        for (int mt = 0; mt < 2; ++mt)
#pragma unroll
            for (int r = 0; r < 4; ++r) {
                int q = w * 32 + mt * 16 + g * 4 + r;
                MlW[q]       = mreg[mt][r];
                MlW[128 + q] = lreg[mt][r];
            }
    }
}

// ---------------------------------------------------------------- merge (4 partials)
__global__ __launch_bounds__(256) void mrgk(
    const f16* __restrict__ Op, const float* __restrict__ Ml,
    const float* __restrict__ xv, const float* __restrict__ gp, const float* __restrict__ bp,
    float* __restrict__ out)
{
    const int bx = blockIdx.x;                 // (b*32+qt)*4 + cg
    const int cg = bx & 3, bqt = bx >> 2;
    const int b = bqt >> 5, qt = bqt & 31;
    const int tid = threadIdx.x;
    const int q = tid & 127, hf = tid >> 7;

    const float* ml = Ml + (size_t)bqt * 4 * 256;
    float m = -1e30f;
#pragma unroll
    for (int kh = 0; kh < 4; ++kh) m = fmaxf(m, ml[kh * 256 + q]);
    float wt[4], tot = 0.f;
#pragma unroll
    for (int kh = 0; kh < 4; ++kh) {
        wt[kh] = exp2f((ml[kh * 256 + q] - m) * L2E);
        tot += wt[kh] * ml[kh * 256 + 128 + q];
    }
    float inv = 1.f / tot;
    float gm = gp[0], bb = bp[0];

    const f16* O = Op + (size_t)bqt * 4 * 16384;
#pragma unroll 4
    for (int i = 0; i < 16; ++i) {
        int c = cg * 32 + hf * 16 + i;
        float o = 0.f;
#pragma unroll
        for (int kh = 0; kh < 4; ++kh) o += wt[kh] * (float)O[kh * 16384 + c * 128 + q];
        o *= inv;
        size_t idx = ((size_t)(b * CC + c)) * SS + qt * 128 + q;
        out[idx] = gm * o + bb * xv[idx];
    }
}

// ---------------------------------------------------------------- launcher
extern "C" void kernel_launch(void* const* d_in, const int* in_sizes, int n_in,
                              void* d_out, int out_size, void* d_ws, size_t ws_size,
                              hipStream_t stream) {
    (void)in_sizes; (void)n_in; (void)out_size; (void)ws_size;

    const size_t TEN = (size_t)BN * SS * CC;         // 2,097,152
    f16* Qt = (f16*)d_ws;                            // 4 MB
    f16* Kt = Qt + TEN;                              // 4 MB
    f16* Vt = Kt + TEN;                              // 4 MB (channel-major)
    f16* Op = Vt + TEN;                              // 512*16384 f16 = 16 MB
    float* Ml = (float*)(Op + (size_t)512 * 16384);  // 512*256 f32 = 512 KB
    f16* Weff = (f16*)(Ml + 131072);                 // 96 KB
    float* ebv = (float*)(Weff + 49152);             // 1.5 KB

    WPrep pq = { (const float*)d_in[3],  (const float*)d_in[4],  (const float*)d_in[5],
                 (const float*)d_in[6],  (const float*)d_in[7],  (const float*)d_in[8] };
    WPrep pk = { (const float*)d_in[9],  (const float*)d_in[10], (const float*)d_in[11],
                 (const float*)d_in[12], (const float*)d_in[13], (const float*)d_in[14] };
    WPrep pv = { (const float*)d_in[15], (const float*)d_in[16], (const float*)d_in[17],
                 (const float*)d_in[18], (const float*)d_in[19], (const float*)d_in[20] };

    hipLaunchKernelGGL(prepk, dim3(192), dim3(256), 0, stream, pq, pk, pv, Weff, ebv);
    hipLaunchKernelGGL(projk, dim3(256, 3), dim3(256), 0, stream,
                       (const float*)d_in[0], (const float*)d_in[1], (const float*)d_in[2],
                       Weff, ebv, Qt, Kt, Vt);
    hipLaunchKernelGGL(attnk, dim3(512), dim3(256), 0, stream, Qt, Kt, Vt, Op, Ml);
    hipLaunchKernelGGL(mrgk, dim3(512), dim3(256), 0, stream,
                       Op, Ml, (const float*)d_in[2], (const float*)d_in[21],
                       (const float*)d_in[22], (float*)d_out);
}